// Round 3
// baseline (745.251 us; speedup 1.0000x reference)
//
#include <hip/hip_runtime.h>

#define NEG_SLOPE 0.2f
#define TSHIFT 12          // src tile = 4096 nodes (2 MB of h) for L2 locality

// ---------------------------------------------------------------------------
// float<->ordered-uint encoding for atomicMax on floats
// ---------------------------------------------------------------------------
__device__ inline unsigned enc_max(float f) {
    unsigned b = __float_as_uint(f);
    return (b & 0x80000000u) ? ~b : (b | 0x80000000u);
}
__device__ inline float dec_max(unsigned k) {
    return (k & 0x80000000u) ? __uint_as_float(k ^ 0x80000000u)
                             : __uint_as_float(~k);
}

// ---------------------------------------------------------------------------
// GEMM + attention projections.
//   H[r,:] = X[r,:] @ W  (128x128); AL[r] = (als_h0, als_h1, ald_h0, ald_h1)
// W staged in LDS as per-lane channel-pair rows: Wp[l][kp] holds
// (W[2kp][2l], W[2kp][2l+1], W[2kp+1][2l], W[2kp+1][2l+1]), XOR-swizzled by
// (l&7) so wave64 b128 reads are bank-conflict-free. x rows are read via
// wave-uniform scalar loads (readfirstlane on wave id -> s_load).
// 512 threads = 8 waves, 16 rows/wave, LDS exactly 64 KB -> 2 blocks/CU.
// ---------------------------------------------------------------------------
__device__ inline void row_out(int r, int N, int lane, float A0, float A1,
                               float as0, float as1, float ad0, float ad1,
                               float* __restrict__ H, float* __restrict__ AL)
{
    if (r >= N) return;
    ((float2*)H)[(size_t)r * 64 + lane] = make_float2(A0, A1);
    float ps = A0 * as0 + A1 * as1;
    float pd = A0 * ad0 + A1 * ad1;
#pragma unroll
    for (int off = 16; off > 0; off >>= 1) {   // reduce within each 32-lane head
        ps += __shfl_xor(ps, off, 64);
        pd += __shfl_xor(pd, off, 64);
    }
    if (lane == 0)       { AL[(size_t)r * 4 + 0] = ps; AL[(size_t)r * 4 + 2] = pd; }
    else if (lane == 32) { AL[(size_t)r * 4 + 1] = ps; AL[(size_t)r * 4 + 3] = pd; }
}

template <bool FULL>
__device__ inline void gemm_rows8(const float* __restrict__ X, int r0, int N,
                                  const float4* __restrict__ WpL, int sw,
                                  float2 (&acc)[8])
{
#pragma unroll 2
    for (int k0 = 0; k0 < 128; k0 += 4) {
        const int kp = k0 >> 1;
        const float4 wA = WpL[kp ^ sw];
        const float4 wB = WpL[(kp + 1) ^ sw];
#pragma unroll
        for (int r = 0; r < 8; r++) {
            float4 xr;
            if (FULL || (r0 + r < N)) {
                xr = *(const float4*)(X + (size_t)(r0 + r) * 128 + k0);
            } else {
                xr = make_float4(0.f, 0.f, 0.f, 0.f);
            }
            acc[r].x = fmaf(xr.x, wA.x, acc[r].x);
            acc[r].y = fmaf(xr.x, wA.y, acc[r].y);
            acc[r].x = fmaf(xr.y, wA.z, acc[r].x);
            acc[r].y = fmaf(xr.y, wA.w, acc[r].y);
            acc[r].x = fmaf(xr.z, wB.x, acc[r].x);
            acc[r].y = fmaf(xr.z, wB.y, acc[r].y);
            acc[r].x = fmaf(xr.w, wB.z, acc[r].x);
            acc[r].y = fmaf(xr.w, wB.w, acc[r].y);
        }
    }
}

__global__ __launch_bounds__(512) void gemm_al_kernel(
    const float* __restrict__ X, const float* __restrict__ W,
    const float* __restrict__ asrc, const float* __restrict__ adst,
    float* __restrict__ H, float* __restrict__ AL, int N)
{
    __shared__ float4 Wp[64 * 64];   // exactly 64 KiB

    const int t = threadIdx.x;
    const int lane = t & 63;
    {
        const float2* Wg = (const float2*)W;   // [k][64] channel-pairs
        const int kp0 = (t >> 6) * 8;
#pragma unroll
        for (int i = 0; i < 8; i++) {
            const int kp = kp0 + i;
            float2 w0 = Wg[(2 * kp) * 64 + lane];
            float2 w1 = Wg[(2 * kp + 1) * 64 + lane];
            Wp[lane * 64 + (kp ^ (lane & 7))] = make_float4(w0.x, w0.y, w1.x, w1.y);
        }
    }
    __syncthreads();

    const int wave = __builtin_amdgcn_readfirstlane(t >> 6);
    const float as0 = asrc[2 * lane], as1 = asrc[2 * lane + 1];
    const float ad0 = adst[2 * lane], ad1 = adst[2 * lane + 1];
    const int sw = lane & 7;
    const float4* WpL = Wp + lane * 64;

    const int rowbase = (blockIdx.x * 8 + wave) * 16;
    for (int half = 0; half < 2; half++) {
        const int r0 = rowbase + half * 8;
        if (r0 >= N) break;
        float2 acc[8];
#pragma unroll
        for (int r = 0; r < 8; r++) acc[r] = make_float2(0.f, 0.f);

        if (r0 + 8 <= N) gemm_rows8<true>(X, r0, N, WpL, sw, acc);
        else             gemm_rows8<false>(X, r0, N, WpL, sw, acc);

#pragma unroll
        for (int r = 0; r < 8; r++)
            row_out(r0 + r, N, lane, acc[r].x, acc[r].y, as0, as1, ad0, ad1, H, AL);
    }
}

// ---------------------------------------------------------------------------
// Global max of al_src per head (upper bound for softmax shift)
// ---------------------------------------------------------------------------
__global__ void almax_kernel(const float* __restrict__ AL,
                             unsigned* __restrict__ ub, int N)
{
    float m0 = -__builtin_inff(), m1 = -__builtin_inff();
    for (int i = blockIdx.x * 256 + threadIdx.x; i < N; i += gridDim.x * 256) {
        m0 = fmaxf(m0, AL[(size_t)i * 4 + 0]);
        m1 = fmaxf(m1, AL[(size_t)i * 4 + 1]);
    }
#pragma unroll
    for (int off = 32; off > 0; off >>= 1) {
        m0 = fmaxf(m0, __shfl_xor(m0, off, 64));
        m1 = fmaxf(m1, __shfl_xor(m1, off, 64));
    }
    if ((threadIdx.x & 63) == 0) {
        atomicMax(&ub[0], enc_max(m0));
        atomicMax(&ub[1], enc_max(m1));
    }
}

// ---------------------------------------------------------------------------
// Bucketed CSR build: bucket = (dst, src>>TSHIFT). Buckets of one dst are
// contiguous, so per-dst ranges are unchanged; edges end up tile-sorted by
// src within each dst list (L2 locality in the gather phase).
// ---------------------------------------------------------------------------
__global__ void count_bucket_kernel(const int* __restrict__ esrc,
                                    const int* __restrict__ edst,
                                    int* __restrict__ bcnt, int E, int N, int NT)
{
    int i = blockIdx.x * 256 + threadIdx.x;
    int s, d;
    if (i < E)          { s = esrc[i]; d = edst[i]; }
    else if (i < E + N) { s = d = i - E; }           // self loop
    else return;
    atomicAdd(&bcnt[d * NT + (s >> TSHIFT)], 1);
}

__global__ void scan_local_kernel(const int* __restrict__ in, int* __restrict__ out,
                                  int* __restrict__ bsum, int n)
{
    __shared__ int sm[1024];
    const int t = threadIdx.x;
    const int i = blockIdx.x * 1024 + t;
    int v = (i < n) ? in[i] : 0;
    sm[t] = v;
    __syncthreads();
    for (int off = 1; off < 1024; off <<= 1) {
        int x = (t >= off) ? sm[t - off] : 0;
        __syncthreads();
        sm[t] += x;
        __syncthreads();
    }
    if (i < n) out[i] = sm[t];
    if (t == 1023) bsum[blockIdx.x] = sm[t];
}

__global__ void scan_excl_single_kernel(int* __restrict__ a, int B)
{
    __shared__ int sm[1024];
    const int t = threadIdx.x;
    int v = (t < B) ? a[t] : 0;
    sm[t] = v;
    __syncthreads();
    for (int off = 1; off < 1024; off <<= 1) {
        int x = (t >= off) ? sm[t - off] : 0;
        __syncthreads();
        sm[t] += x;
        __syncthreads();
    }
    if (t < B) a[t] = sm[t] - v;   // exclusive
}

__global__ void addback_kernel(int* __restrict__ a, const int* __restrict__ bexcl, int n)
{
    const int i = blockIdx.x * 1024 + threadIdx.x;
    if (i < n) a[i] += bexcl[i >> 10];
}

__global__ void finalize_kernel(const int* __restrict__ incl, const int* __restrict__ bcnt,
                                const int* __restrict__ bs1incl, int* __restrict__ cursor,
                                int NB)
{
    const int i = blockIdx.x * 1024 + threadIdx.x;
    if (i >= NB) return;
    const int b = i >> 10;
    const int off = b ? bs1incl[b - 1] : 0;
    cursor[i] = incl[i] - bcnt[i] + off;   // global exclusive scan
}

__global__ void dstptr_kernel(const int* __restrict__ cursor, int* __restrict__ dstptr,
                              int N, int NT, int Etot)
{
    const int d = blockIdx.x * 256 + threadIdx.x;
    if (d < N) dstptr[d] = cursor[d * NT];
    if (d == 0) dstptr[N] = Etot;
}

__global__ void scatter_kernel(const int* __restrict__ esrc, const int* __restrict__ edst,
                               int* __restrict__ cursor, int* __restrict__ ssrc,
                               int E, int N, int NT)
{
    int i = blockIdx.x * 256 + threadIdx.x;
    int s, d;
    if (i < E)          { s = esrc[i]; d = edst[i]; }
    else if (i < E + N) { s = d = i - E; }
    else return;
    int pos = atomicAdd(&cursor[d * NT + (s >> TSHIFT)], 1);
    ssrc[pos] = s;
}

// ---------------------------------------------------------------------------
// Per-destination aggregation, shifted softmax. One wave per node.
// 3-deep pipeline over 4-edge blocks: ssrc j+12 | AL,h j+8 | compute j.
// ---------------------------------------------------------------------------
__global__ __launch_bounds__(256) void aggregate_kernel(
    const float* __restrict__ H, const float* __restrict__ AL,
    const int* __restrict__ dstptr, const int* __restrict__ ssrc,
    const unsigned* __restrict__ ubenc, const float* __restrict__ bias,
    float* __restrict__ out, int N, int mode)
{
    const int w = (blockIdx.x * blockDim.x + threadIdx.x) >> 6;
    const int lane = threadIdx.x & 63;
    if (w >= N) return;
    const int n = w;

    const int beg = dstptr[n], end = dstptr[n + 1];
    const int head = lane >> 5;
    const float ald = AL[(size_t)n * 4 + 2 + head];
    float ub = dec_max(ubenc[head]) + ald;
    ub = (ub >= 0.f) ? ub : NEG_SLOPE * ub;

    float s = 0.f, ax = 0.f, ay = 0.f;

    float e0[4], e1[4];
    float2 h0[4], h1[4];
    int sA[4];

    {   // prologue: ALH blocks 0,1 issued; srcs of block 2 staged
        int ta[4], tb[4];
#pragma unroll
        for (int k = 0; k < 4; k++) { int i = beg + k;     int v = ssrc[i]; ta[k] = (i < end) ? v : 0; }
#pragma unroll
        for (int k = 0; k < 4; k++) { int i = beg + 4 + k; int v = ssrc[i]; tb[k] = (i < end) ? v : 0; }
#pragma unroll
        for (int k = 0; k < 4; k++) { int i = beg + 8 + k; int v = ssrc[i]; sA[k] = (i < end) ? v : 0; }
#pragma unroll
        for (int k = 0; k < 4; k++) {
            int i = beg + k;
            float a = AL[(size_t)ta[k] * 4 + head];
            e0[k] = (i < end) ? a : -__builtin_inff();
            h0[k] = *(const float2*)(H + (size_t)ta[k] * 128 + 2 * lane);
        }
#pragma unroll
        for (int k = 0; k < 4; k++) {
            int i = beg + 4 + k;
            float a = AL[(size_t)tb[k] * 4 + head];
            e1[k] = (i < end) ? a : -__builtin_inff();
            h1[k] = *(const float2*)(H + (size_t)tb[k] * 128 + 2 * lane);
        }
    }

#pragma unroll 2
    for (int j = beg; j < end; j += 4) {
        int sB[4];
#pragma unroll
        for (int k = 0; k < 4; k++) { int i = j + 12 + k; int v = ssrc[i]; sB[k] = (i < end) ? v : 0; }
        float e2[4]; float2 h2[4];
#pragma unroll
        for (int k = 0; k < 4; k++) {
            int i = j + 8 + k;
            float a = AL[(size_t)sA[k] * 4 + head];
            e2[k] = (i < end) ? a : -__builtin_inff();
            h2[k] = *(const float2*)(H + (size_t)sA[k] * 128 + 2 * lane);
        }
#pragma unroll
        for (int k = 0; k < 4; k++) {
            float t = e0[k] + ald;                   // -inf for masked slots
            t = (t >= 0.f) ? t : NEG_SLOPE * t;
            const float p = __expf(t - ub);          // exp(-inf)=0
            s += p;
            ax = fmaf(p, h0[k].x, ax);
            ay = fmaf(p, h0[k].y, ay);
        }
#pragma unroll
        for (int k = 0; k < 4; k++) {
            e0[k] = e1[k]; h0[k] = h1[k];
            e1[k] = e2[k]; h1[k] = h2[k];
            sA[k] = sB[k];
        }
    }

    const float inv = 1.f / s;                       // s > 0 (self loop)
    float o0 = ax * inv, o1 = ay * inv;

    if (mode == 0) {
        o0 += bias[2 * lane]; o1 += bias[2 * lane + 1];
        o0 = (o0 > 0.f) ? o0 : (__expf(o0) - 1.f);   // ELU
        o1 = (o1 > 0.f) ? o1 : (__expf(o1) - 1.f);
        ((float2*)out)[(size_t)n * 64 + lane] = make_float2(o0, o1);
    } else {
        const float p0 = __shfl_xor(o0, 32, 64);
        const float p1 = __shfl_xor(o1, 32, 64);
        if (lane < 32) {
            const float r0 = 0.5f * (o0 + p0) + bias[2 * lane];
            const float r1 = 0.5f * (o1 + p1) + bias[2 * lane + 1];
            ((float2*)out)[(size_t)n * 32 + lane] = make_float2(r0, r1);
        }
    }
}

// ---------------------------------------------------------------------------
extern "C" void kernel_launch(void* const* d_in, const int* in_sizes, int n_in,
                              void* d_out, int out_size, void* d_ws, size_t ws_size,
                              hipStream_t stream)
{
    const float* x   = (const float*)d_in[0];
    const int*   eix = (const int*)d_in[1];   // [2, E] int32
    const float* W1  = (const float*)d_in[2];
    const float* as1 = (const float*)d_in[3];
    const float* ad1 = (const float*)d_in[4];
    const float* b1  = (const float*)d_in[5];
    const float* W2  = (const float*)d_in[6];
    const float* as2 = (const float*)d_in[7];
    const float* ad2 = (const float*)d_in[8];
    const float* b2  = (const float*)d_in[9];
    float* out = (float*)d_out;

    const int N = in_sizes[0] / 128;
    const int E = in_sizes[1] / 2;
    const int Etot = E + N;
    const int* esrc = eix;
    const int* edst = eix + E;

    const int NT = ((N - 1) >> TSHIFT) + 1;           // # src tiles (25)
    const int NB = N * NT;                            // # buckets (2.5M)

    // ---- workspace layout (persistent ~111 MB; CSR scratch overlaps y1) ----
    char* p = (char*)d_ws;
    float*    h      = (float*)p;    p += (size_t)N * 128 * 4;
    float*    y1     = (float*)p;    p += (size_t)N * 128 * 4;
    float*    al     = (float*)p;    p += (size_t)N * 4 * 4;
    unsigned* ub     = (unsigned*)p; p += 64;                 // ub[0..1] L1, [2..3] L2
    int*      dstptr = (int*)p;      p += (size_t)(N + 1) * 4;
    int*      ssrc   = (int*)p;      p += (size_t)(Etot + 32) * 4;  // pad for pipeline

    // scratch inside y1 (y1 written only later, by aggregate L1)
    char* q = (char*)y1;
    int* bcnt   = (int*)q; q += (size_t)NB * 4;
    int* incl   = (int*)q; q += (size_t)NB * 4;
    int* cursor = (int*)q; q += (size_t)NB * 4;
    int* bs1    = (int*)q; q += 4096 * 4;
    int* bs2    = (int*)q; q += 1024 * 4;

    hipMemsetAsync(bcnt, 0, (size_t)NB * 4, stream);
    hipMemsetAsync(ub, 0, 64, stream);                // enc(-inf) > 0, 0 is safe floor

    // ---- bucketed CSR (shared by both layers) ----
    {
        const int eblocks = (Etot + 255) / 256;
        const int B0 = (NB + 1023) / 1024;            // 2442
        const int B1 = (B0 + 1023) / 1024;            // 3
        count_bucket_kernel<<<eblocks, 256, 0, stream>>>(esrc, edst, bcnt, E, N, NT);
        scan_local_kernel<<<B0, 1024, 0, stream>>>(bcnt, incl, bs1, NB);
        scan_local_kernel<<<B1, 1024, 0, stream>>>(bs1, bs1, bs2, B0);
        scan_excl_single_kernel<<<1, 1024, 0, stream>>>(bs2, B1);
        addback_kernel<<<B1, 1024, 0, stream>>>(bs1, bs2, B0);
        finalize_kernel<<<B0, 1024, 0, stream>>>(incl, bcnt, bs1, cursor, NB);
        dstptr_kernel<<<(N + 255) / 256, 256, 0, stream>>>(cursor, dstptr, N, NT, Etot);
        scatter_kernel<<<eblocks, 256, 0, stream>>>(esrc, edst, cursor, ssrc, E, N, NT);
    }

    const int ggrid = (N + 127) / 128;                       // 128 rows/block
    const int ablocks = (int)(((size_t)N * 64 + 255) / 256); // 1 wave/node

    // ---- Layer 1 ----
    gemm_al_kernel<<<ggrid, 512, 0, stream>>>(x, W1, as1, ad1, h, al, N);
    almax_kernel<<<256, 256, 0, stream>>>(al, ub, N);
    aggregate_kernel<<<ablocks, 256, 0, stream>>>(h, al, dstptr, ssrc, ub, b1, y1, N, 0);

    // ---- Layer 2 ----
    gemm_al_kernel<<<ggrid, 512, 0, stream>>>(y1, W2, as2, ad2, h, al, N);
    almax_kernel<<<256, 256, 0, stream>>>(al, ub + 2, N);
    aggregate_kernel<<<ablocks, 256, 0, stream>>>(h, al, dstptr, ssrc, ub + 2, b2, out, N, 1);
}

// Round 4
// 649.430 us; speedup vs baseline: 1.1475x; 1.1475x over previous
//
#include <hip/hip_runtime.h>

#define NEG_SLOPE 0.2f
#define TSHIFT 12          // src tile = 4096 nodes (2 MB of h) for L2 locality

// ---------------------------------------------------------------------------
// float<->ordered-uint encoding for atomicMax on floats
// ---------------------------------------------------------------------------
__device__ inline unsigned enc_max(float f) {
    unsigned b = __float_as_uint(f);
    return (b & 0x80000000u) ? ~b : (b | 0x80000000u);
}
__device__ inline float dec_max(unsigned k) {
    return (k & 0x80000000u) ? __uint_as_float(k ^ 0x80000000u)
                             : __uint_as_float(~k);
}

// ---------------------------------------------------------------------------
// GEMM + attention projections.
//   H[r,:] = X[r,:] @ W  (128x128); AL[r] = (als_h0, als_h1, ald_h0, ald_h1)
// 512 threads = 8 waves, 16 rows/wave in 4-row chunks.
// W in LDS, natural contiguous-lane float4 layout (b128 reads, conflict-free):
//   WA[kq][l] = (W[4kq+0][2l], W[4kq+0][2l+1], W[4kq+1][2l], W[4kq+1][2l+1])
//   WB[kq][l] = same for 4kq+2, 4kq+3
// x rows staged per-wave in LDS, read back as same-address b128 broadcasts.
// LDS = 32+32+16 = 80 KB -> 2 blocks/CU -> 4 waves/SIMD.
// ---------------------------------------------------------------------------
__device__ inline void row_out(int r, int N, int lane, float A0, float A1,
                               float as0, float as1, float ad0, float ad1,
                               float* __restrict__ H, float* __restrict__ AL)
{
    if (r >= N) return;
    ((float2*)H)[(size_t)r * 64 + lane] = make_float2(A0, A1);
    float ps = A0 * as0 + A1 * as1;
    float pd = A0 * ad0 + A1 * ad1;
#pragma unroll
    for (int off = 16; off > 0; off >>= 1) {   // reduce within each 32-lane head
        ps += __shfl_xor(ps, off, 64);
        pd += __shfl_xor(pd, off, 64);
    }
    if (lane == 0)       { AL[(size_t)r * 4 + 0] = ps; AL[(size_t)r * 4 + 2] = pd; }
    else if (lane == 32) { AL[(size_t)r * 4 + 1] = ps; AL[(size_t)r * 4 + 3] = pd; }
}

__global__ __launch_bounds__(512) void gemm_al_kernel(
    const float* __restrict__ X, const float* __restrict__ W,
    const float* __restrict__ asrc, const float* __restrict__ adst,
    float* __restrict__ H, float* __restrict__ AL, int N)
{
    __shared__ float4 WA[32 * 64];     // 32 KiB
    __shared__ float4 WB[32 * 64];     // 32 KiB
    __shared__ float  xb[8][4][128];   // 16 KiB (per-wave 4-row staging)

    const int t = threadIdx.x, lane = t & 63, wave = t >> 6;

    // stage W (one-time, 64 KB)
    {
        const float2* Wg = (const float2*)W;   // [k][64 channel-pairs]
#pragma unroll
        for (int idx = t; idx < 2048; idx += 512) {
            const int kq = idx >> 6, l = idx & 63;
            float2 a0 = Wg[(4 * kq + 0) * 64 + l];
            float2 a1 = Wg[(4 * kq + 1) * 64 + l];
            float2 b0 = Wg[(4 * kq + 2) * 64 + l];
            float2 b1 = Wg[(4 * kq + 3) * 64 + l];
            WA[kq * 64 + l] = make_float4(a0.x, a0.y, a1.x, a1.y);
            WB[kq * 64 + l] = make_float4(b0.x, b0.y, b1.x, b1.y);
        }
    }
    __syncthreads();

    const float as0 = asrc[2 * lane], as1 = asrc[2 * lane + 1];
    const float ad0 = adst[2 * lane], ad1 = adst[2 * lane + 1];

    const int i0 = lane, i1 = lane + 64;       // float4 slots within 4x128 chunk
    const int r0i = i0 >> 5, k0i = i0 & 31;
    const int r1i = i1 >> 5, k1i = i1 & 31;
    const int rowbase = (blockIdx.x * 8 + wave) * 16;

    // prefetch chunk 0
    float4 pA = make_float4(0, 0, 0, 0), pB = make_float4(0, 0, 0, 0);
    if (rowbase + r0i < N) pA = ((const float4*)(X + (size_t)(rowbase + r0i) * 128))[k0i];
    if (rowbase + r1i < N) pB = ((const float4*)(X + (size_t)(rowbase + r1i) * 128))[k1i];

    for (int c = 0; c < 4; c++) {
        const int rbase = rowbase + c * 4;
        if (rbase >= N) break;

        ((float4*)xb[wave][r0i])[k0i] = pA;    // waits vmcnt for pA/pB
        ((float4*)xb[wave][r1i])[k1i] = pB;

        if (c < 3) {                           // issue next chunk's loads
            const int nb = rowbase + (c + 1) * 4;
            pA = make_float4(0, 0, 0, 0); pB = make_float4(0, 0, 0, 0);
            if (nb + r0i < N) pA = ((const float4*)(X + (size_t)(nb + r0i) * 128))[k0i];
            if (nb + r1i < N) pB = ((const float4*)(X + (size_t)(nb + r1i) * 128))[k1i];
        }

        float2 acc[4];
#pragma unroll
        for (int r = 0; r < 4; r++) acc[r] = make_float2(0.f, 0.f);

#pragma unroll 4
        for (int kq = 0; kq < 32; kq++) {
            const float4 wA = WA[kq * 64 + lane];   // contiguous-lane b128
            const float4 wB = WB[kq * 64 + lane];
#pragma unroll
            for (int r = 0; r < 4; r++) {
                const float4 xr = ((const float4*)xb[wave][r])[kq];  // broadcast
                acc[r].x = fmaf(xr.x, wA.x, acc[r].x);
                acc[r].y = fmaf(xr.x, wA.y, acc[r].y);
                acc[r].x = fmaf(xr.y, wA.z, acc[r].x);
                acc[r].y = fmaf(xr.y, wA.w, acc[r].y);
                acc[r].x = fmaf(xr.z, wB.x, acc[r].x);
                acc[r].y = fmaf(xr.z, wB.y, acc[r].y);
                acc[r].x = fmaf(xr.w, wB.z, acc[r].x);
                acc[r].y = fmaf(xr.w, wB.w, acc[r].y);
            }
        }
#pragma unroll
        for (int r = 0; r < 4; r++)
            row_out(rbase + r, N, lane, acc[r].x, acc[r].y, as0, as1, ad0, ad1, H, AL);
    }
}

// ---------------------------------------------------------------------------
// Global max of al_src per head (upper bound for softmax shift)
// ---------------------------------------------------------------------------
__global__ void almax_kernel(const float* __restrict__ AL,
                             unsigned* __restrict__ ub, int N)
{
    float m0 = -__builtin_inff(), m1 = -__builtin_inff();
    for (int i = blockIdx.x * 256 + threadIdx.x; i < N; i += gridDim.x * 256) {
        m0 = fmaxf(m0, AL[(size_t)i * 4 + 0]);
        m1 = fmaxf(m1, AL[(size_t)i * 4 + 1]);
    }
#pragma unroll
    for (int off = 32; off > 0; off >>= 1) {
        m0 = fmaxf(m0, __shfl_xor(m0, off, 64));
        m1 = fmaxf(m1, __shfl_xor(m1, off, 64));
    }
    if ((threadIdx.x & 63) == 0) {
        atomicMax(&ub[0], enc_max(m0));
        atomicMax(&ub[1], enc_max(m1));
    }
}

// ---------------------------------------------------------------------------
// Bucketed CSR build: bucket = (dst, src>>TSHIFT).
// ---------------------------------------------------------------------------
__global__ void count_bucket_kernel(const int* __restrict__ esrc,
                                    const int* __restrict__ edst,
                                    int* __restrict__ bcnt, int E, int N, int NT)
{
    int i = blockIdx.x * 256 + threadIdx.x;
    int s, d;
    if (i < E)          { s = esrc[i]; d = edst[i]; }
    else if (i < E + N) { s = d = i - E; }           // self loop
    else return;
    atomicAdd(&bcnt[d * NT + (s >> TSHIFT)], 1);
}

__global__ void scan_local_kernel(const int* __restrict__ in, int* __restrict__ out,
                                  int* __restrict__ bsum, int n)
{
    __shared__ int sm[1024];
    const int t = threadIdx.x;
    const int i = blockIdx.x * 1024 + t;
    int v = (i < n) ? in[i] : 0;
    sm[t] = v;
    __syncthreads();
    for (int off = 1; off < 1024; off <<= 1) {
        int x = (t >= off) ? sm[t - off] : 0;
        __syncthreads();
        sm[t] += x;
        __syncthreads();
    }
    if (i < n) out[i] = sm[t];
    if (t == 1023) bsum[blockIdx.x] = sm[t];
}

__global__ void scan_excl_single_kernel(int* __restrict__ a, int B)
{
    __shared__ int sm[1024];
    const int t = threadIdx.x;
    int v = (t < B) ? a[t] : 0;
    sm[t] = v;
    __syncthreads();
    for (int off = 1; off < 1024; off <<= 1) {
        int x = (t >= off) ? sm[t - off] : 0;
        __syncthreads();
        sm[t] += x;
        __syncthreads();
    }
    if (t < B) a[t] = sm[t] - v;   // exclusive
}

__global__ void addback_kernel(int* __restrict__ a, const int* __restrict__ bexcl, int n)
{
    const int i = blockIdx.x * 1024 + threadIdx.x;
    if (i < n) a[i] += bexcl[i >> 10];
}

__global__ void finalize_kernel(const int* __restrict__ incl, const int* __restrict__ bcnt,
                                const int* __restrict__ bs1incl, int* __restrict__ cursor,
                                int NB)
{
    const int i = blockIdx.x * 1024 + threadIdx.x;
    if (i >= NB) return;
    const int b = i >> 10;
    const int off = b ? bs1incl[b - 1] : 0;
    cursor[i] = incl[i] - bcnt[i] + off;   // global exclusive scan
}

__global__ void dstptr_kernel(const int* __restrict__ cursor, int* __restrict__ dstptr,
                              int N, int NT, int Etot)
{
    const int d = blockIdx.x * 256 + threadIdx.x;
    if (d < N) dstptr[d] = cursor[d * NT];
    if (d == 0) dstptr[N] = Etot;
}

// Sliced scatter: blocks with blockIdx%8==s handle dst slice s (-> one XCD by
// round-robin dispatch), so each ssrc cache line is written by one XCD only.
__global__ void scatter_kernel(const int* __restrict__ esrc, const int* __restrict__ edst,
                               int* __restrict__ cursor, int* __restrict__ ssrc,
                               int E, int N, int NT, int sliceN, int bps)
{
    const int slice = blockIdx.x & 7;
    const int dlo = slice * sliceN;
    const int dhi = min(N, dlo + sliceN);
    const int Etot = E + N;
    for (int i = (blockIdx.x >> 3) * 256 + (int)threadIdx.x; i < Etot; i += bps * 256) {
        int s, d;
        if (i < E) { s = esrc[i]; d = edst[i]; }
        else       { s = d = i - E; }
        if (d >= dlo && d < dhi) {
            int pos = atomicAdd(&cursor[d * NT + (s >> TSHIFT)], 1);
            ssrc[pos] = s;
        }
    }
}

// ---------------------------------------------------------------------------
// Per-destination aggregation, shifted softmax. One wave per node.
// 3-deep pipeline over 4-edge blocks: ssrc j+12 | AL,h j+8 | compute j.
// ---------------------------------------------------------------------------
__global__ __launch_bounds__(256) void aggregate_kernel(
    const float* __restrict__ H, const float* __restrict__ AL,
    const int* __restrict__ dstptr, const int* __restrict__ ssrc,
    const unsigned* __restrict__ ubenc, const float* __restrict__ bias,
    float* __restrict__ out, int N, int mode)
{
    const int w = (blockIdx.x * blockDim.x + threadIdx.x) >> 6;
    const int lane = threadIdx.x & 63;
    if (w >= N) return;
    const int n = w;

    const int beg = dstptr[n], end = dstptr[n + 1];
    const int head = lane >> 5;
    const float ald = AL[(size_t)n * 4 + 2 + head];
    float ub = dec_max(ubenc[head]) + ald;
    ub = (ub >= 0.f) ? ub : NEG_SLOPE * ub;

    float s = 0.f, ax = 0.f, ay = 0.f;

    float e0[4], e1[4];
    float2 h0[4], h1[4];
    int sA[4];

    {   // prologue: ALH blocks 0,1 issued; srcs of block 2 staged
        int ta[4], tb[4];
#pragma unroll
        for (int k = 0; k < 4; k++) { int i = beg + k;     int v = ssrc[i]; ta[k] = (i < end) ? v : 0; }
#pragma unroll
        for (int k = 0; k < 4; k++) { int i = beg + 4 + k; int v = ssrc[i]; tb[k] = (i < end) ? v : 0; }
#pragma unroll
        for (int k = 0; k < 4; k++) { int i = beg + 8 + k; int v = ssrc[i]; sA[k] = (i < end) ? v : 0; }
#pragma unroll
        for (int k = 0; k < 4; k++) {
            int i = beg + k;
            float a = AL[(size_t)ta[k] * 4 + head];
            e0[k] = (i < end) ? a : -__builtin_inff();
            h0[k] = *(const float2*)(H + (size_t)ta[k] * 128 + 2 * lane);
        }
#pragma unroll
        for (int k = 0; k < 4; k++) {
            int i = beg + 4 + k;
            float a = AL[(size_t)tb[k] * 4 + head];
            e1[k] = (i < end) ? a : -__builtin_inff();
            h1[k] = *(const float2*)(H + (size_t)tb[k] * 128 + 2 * lane);
        }
    }

#pragma unroll 2
    for (int j = beg; j < end; j += 4) {
        int sB[4];
#pragma unroll
        for (int k = 0; k < 4; k++) { int i = j + 12 + k; int v = ssrc[i]; sB[k] = (i < end) ? v : 0; }
        float e2[4]; float2 h2[4];
#pragma unroll
        for (int k = 0; k < 4; k++) {
            int i = j + 8 + k;
            float a = AL[(size_t)sA[k] * 4 + head];
            e2[k] = (i < end) ? a : -__builtin_inff();
            h2[k] = *(const float2*)(H + (size_t)sA[k] * 128 + 2 * lane);
        }
#pragma unroll
        for (int k = 0; k < 4; k++) {
            float t = e0[k] + ald;                   // -inf for masked slots
            t = (t >= 0.f) ? t : NEG_SLOPE * t;
            const float p = __expf(t - ub);          // exp(-inf)=0
            s += p;
            ax = fmaf(p, h0[k].x, ax);
            ay = fmaf(p, h0[k].y, ay);
        }
#pragma unroll
        for (int k = 0; k < 4; k++) {
            e0[k] = e1[k]; h0[k] = h1[k];
            e1[k] = e2[k]; h1[k] = h2[k];
            sA[k] = sB[k];
        }
    }

    const float inv = 1.f / s;                       // s > 0 (self loop)
    float o0 = ax * inv, o1 = ay * inv;

    if (mode == 0) {
        o0 += bias[2 * lane]; o1 += bias[2 * lane + 1];
        o0 = (o0 > 0.f) ? o0 : (__expf(o0) - 1.f);   // ELU
        o1 = (o1 > 0.f) ? o1 : (__expf(o1) - 1.f);
        ((float2*)out)[(size_t)n * 64 + lane] = make_float2(o0, o1);
    } else {
        const float p0 = __shfl_xor(o0, 32, 64);
        const float p1 = __shfl_xor(o1, 32, 64);
        if (lane < 32) {
            const float r0 = 0.5f * (o0 + p0) + bias[2 * lane];
            const float r1 = 0.5f * (o1 + p1) + bias[2 * lane + 1];
            ((float2*)out)[(size_t)n * 32 + lane] = make_float2(r0, r1);
        }
    }
}

// ---------------------------------------------------------------------------
extern "C" void kernel_launch(void* const* d_in, const int* in_sizes, int n_in,
                              void* d_out, int out_size, void* d_ws, size_t ws_size,
                              hipStream_t stream)
{
    const float* x   = (const float*)d_in[0];
    const int*   eix = (const int*)d_in[1];   // [2, E] int32
    const float* W1  = (const float*)d_in[2];
    const float* as1 = (const float*)d_in[3];
    const float* ad1 = (const float*)d_in[4];
    const float* b1  = (const float*)d_in[5];
    const float* W2  = (const float*)d_in[6];
    const float* as2 = (const float*)d_in[7];
    const float* ad2 = (const float*)d_in[8];
    const float* b2  = (const float*)d_in[9];
    float* out = (float*)d_out;

    const int N = in_sizes[0] / 128;
    const int E = in_sizes[1] / 2;
    const int Etot = E + N;
    const int* esrc = eix;
    const int* edst = eix + E;

    const int NT = ((N - 1) >> TSHIFT) + 1;           // # src tiles
    const int NB = N * NT;                            // # buckets

    // ---- workspace layout (persistent ~111 MB; CSR scratch overlaps y1) ----
    char* p = (char*)d_ws;
    float*    h      = (float*)p;    p += (size_t)N * 128 * 4;
    float*    y1     = (float*)p;    p += (size_t)N * 128 * 4;
    float*    al     = (float*)p;    p += (size_t)N * 4 * 4;
    unsigned* ub     = (unsigned*)p; p += 64;                 // ub[0..1] L1, [2..3] L2
    int*      dstptr = (int*)p;      p += (size_t)(N + 1) * 4;
    int*      ssrc   = (int*)p;      p += (size_t)(Etot + 32) * 4;  // pad for pipeline

    // scratch inside y1 (y1 written only later, by aggregate L1)
    char* q = (char*)y1;
    int* bcnt   = (int*)q; q += (size_t)NB * 4;
    int* incl   = (int*)q; q += (size_t)NB * 4;
    int* cursor = (int*)q; q += (size_t)NB * 4;
    int* bs1    = (int*)q; q += 4096 * 4;
    int* bs2    = (int*)q; q += 1024 * 4;

    hipMemsetAsync(bcnt, 0, (size_t)NB * 4, stream);
    hipMemsetAsync(ub, 0, 64, stream);                // enc floor

    // ---- bucketed CSR (shared by both layers) ----
    {
        const int eblocks = (Etot + 255) / 256;
        const int B0 = (NB + 1023) / 1024;
        const int B1 = (B0 + 1023) / 1024;
        count_bucket_kernel<<<eblocks, 256, 0, stream>>>(esrc, edst, bcnt, E, N, NT);
        scan_local_kernel<<<B0, 1024, 0, stream>>>(bcnt, incl, bs1, NB);
        scan_local_kernel<<<B1, 1024, 0, stream>>>(bs1, bs1, bs2, B0);
        scan_excl_single_kernel<<<1, 1024, 0, stream>>>(bs2, B1);
        addback_kernel<<<B1, 1024, 0, stream>>>(bs1, bs2, B0);
        finalize_kernel<<<B0, 1024, 0, stream>>>(incl, bcnt, bs1, cursor, NB);
        dstptr_kernel<<<(N + 255) / 256, 256, 0, stream>>>(cursor, dstptr, N, NT, Etot);
        const int sliceN = (N + 7) / 8;
        const int bps = 512;                          // blocks per slice
        scatter_kernel<<<bps * 8, 256, 0, stream>>>(esrc, edst, cursor, ssrc,
                                                    E, N, NT, sliceN, bps);
    }

    const int ggrid = (N + 127) / 128;                       // 128 rows/block
    const int ablocks = (int)(((size_t)N * 64 + 255) / 256); // 1 wave/node

    // ---- Layer 1 ----
    gemm_al_kernel<<<ggrid, 512, 0, stream>>>(x, W1, as1, ad1, h, al, N);
    almax_kernel<<<256, 256, 0, stream>>>(al, ub, N);
    aggregate_kernel<<<ablocks, 256, 0, stream>>>(h, al, dstptr, ssrc, ub, b1, y1, N, 0);

    // ---- Layer 2 ----
    gemm_al_kernel<<<ggrid, 512, 0, stream>>>(y1, W2, as2, ad2, h, al, N);
    almax_kernel<<<256, 256, 0, stream>>>(al, ub + 2, N);
    aggregate_kernel<<<ablocks, 256, 0, stream>>>(h, al, dstptr, ssrc, ub + 2, b2, out, N, 1);
}

// Round 5
// 448.077 us; speedup vs baseline: 1.6632x; 1.4494x over previous
//
#include <hip/hip_runtime.h>
#include <hip/hip_fp16.h>

#define NEG_SLOPE 0.2f

// ---------------------------------------------------------------------------
// float<->ordered-uint encoding for atomicMax on floats
// ---------------------------------------------------------------------------
__device__ inline unsigned enc_max(float f) {
    unsigned b = __float_as_uint(f);
    return (b & 0x80000000u) ? ~b : (b | 0x80000000u);
}
__device__ inline float dec_max(unsigned k) {
    return (k & 0x80000000u) ? __uint_as_float(k ^ 0x80000000u)
                             : __uint_as_float(~k);
}

// ---------------------------------------------------------------------------
// GEMM + attention projections.
//   H16[r,:] = fp16(X[r,:] @ W); AL[r] = (als_h0, als_h1, ald_h0, ald_h1)
// Also folds the global max of als per head (softmax shift ub) via per-block
// LDS reduce + 2 atomics. Messages are fp16; logits stay fp32-exact.
// 512 threads = 8 waves, 16 rows/wave in 4-row chunks. LDS 80KB -> 2 blk/CU.
// ---------------------------------------------------------------------------
__device__ inline void row_out(int r, int N, int lane, float A0, float A1,
                               float as0, float as1, float ad0, float ad1,
                               __half* __restrict__ H16, float* __restrict__ AL,
                               float& rmax)
{
    if (r >= N) return;
    ((__half2*)H16)[(size_t)r * 64 + lane] = __float22half2_rn(make_float2(A0, A1));
    float ps = A0 * as0 + A1 * as1;
    float pd = A0 * ad0 + A1 * ad1;
#pragma unroll
    for (int off = 16; off > 0; off >>= 1) {   // reduce within each 32-lane head
        ps += __shfl_xor(ps, off, 64);
        pd += __shfl_xor(pd, off, 64);
    }
    rmax = fmaxf(rmax, ps);                    // valid at lanes 0 (h0) / 32 (h1)
    if (lane == 0)       { AL[(size_t)r * 4 + 0] = ps; AL[(size_t)r * 4 + 2] = pd; }
    else if (lane == 32) { AL[(size_t)r * 4 + 1] = ps; AL[(size_t)r * 4 + 3] = pd; }
}

__global__ __launch_bounds__(512) void gemm_al_kernel(
    const float* __restrict__ X, const float* __restrict__ W,
    const float* __restrict__ asrc, const float* __restrict__ adst,
    __half* __restrict__ H16, float* __restrict__ AL,
    unsigned* __restrict__ ubp, int N)
{
    __shared__ float4 WA[32 * 64];     // 32 KiB
    __shared__ float4 WB[32 * 64];     // 32 KiB
    __shared__ float  xb[8][4][128];   // 16 KiB (per-wave 4-row staging)

    const int t = threadIdx.x, lane = t & 63, wave = t >> 6;

    {   // stage W (one-time, 64 KB)
        const float2* Wg = (const float2*)W;   // [k][64 channel-pairs]
#pragma unroll
        for (int idx = t; idx < 2048; idx += 512) {
            const int kq = idx >> 6, l = idx & 63;
            float2 a0 = Wg[(4 * kq + 0) * 64 + l];
            float2 a1 = Wg[(4 * kq + 1) * 64 + l];
            float2 b0 = Wg[(4 * kq + 2) * 64 + l];
            float2 b1 = Wg[(4 * kq + 3) * 64 + l];
            WA[kq * 64 + l] = make_float4(a0.x, a0.y, a1.x, a1.y);
            WB[kq * 64 + l] = make_float4(b0.x, b0.y, b1.x, b1.y);
        }
    }
    __syncthreads();

    const float as0 = asrc[2 * lane], as1 = asrc[2 * lane + 1];
    const float ad0 = adst[2 * lane], ad1 = adst[2 * lane + 1];

    const int i0 = lane, i1 = lane + 64;       // float4 slots within 4x128 chunk
    const int r0i = i0 >> 5, k0i = i0 & 31;
    const int r1i = i1 >> 5, k1i = i1 & 31;
    const int rowbase = (blockIdx.x * 8 + wave) * 16;
    float rmax = -__builtin_inff();

    // prefetch chunk 0
    float4 pA = make_float4(0, 0, 0, 0), pB = make_float4(0, 0, 0, 0);
    if (rowbase + r0i < N) pA = ((const float4*)(X + (size_t)(rowbase + r0i) * 128))[k0i];
    if (rowbase + r1i < N) pB = ((const float4*)(X + (size_t)(rowbase + r1i) * 128))[k1i];

    for (int c = 0; c < 4; c++) {
        const int rbase = rowbase + c * 4;
        if (rbase >= N) break;

        ((float4*)xb[wave][r0i])[k0i] = pA;
        ((float4*)xb[wave][r1i])[k1i] = pB;

        if (c < 3) {
            const int nb = rowbase + (c + 1) * 4;
            pA = make_float4(0, 0, 0, 0); pB = make_float4(0, 0, 0, 0);
            if (nb + r0i < N) pA = ((const float4*)(X + (size_t)(nb + r0i) * 128))[k0i];
            if (nb + r1i < N) pB = ((const float4*)(X + (size_t)(nb + r1i) * 128))[k1i];
        }

        float2 acc[4];
#pragma unroll
        for (int r = 0; r < 4; r++) acc[r] = make_float2(0.f, 0.f);

#pragma unroll 4
        for (int kq = 0; kq < 32; kq++) {
            const float4 wA = WA[kq * 64 + lane];   // contiguous-lane b128
            const float4 wB = WB[kq * 64 + lane];
#pragma unroll
            for (int r = 0; r < 4; r++) {
                const float4 xr = ((const float4*)xb[wave][r])[kq];  // broadcast
                acc[r].x = fmaf(xr.x, wA.x, acc[r].x);
                acc[r].y = fmaf(xr.x, wA.y, acc[r].y);
                acc[r].x = fmaf(xr.y, wA.z, acc[r].x);
                acc[r].y = fmaf(xr.y, wA.w, acc[r].y);
                acc[r].x = fmaf(xr.z, wB.x, acc[r].x);
                acc[r].y = fmaf(xr.z, wB.y, acc[r].y);
                acc[r].x = fmaf(xr.w, wB.z, acc[r].x);
                acc[r].y = fmaf(xr.w, wB.w, acc[r].y);
            }
        }
#pragma unroll
        for (int r = 0; r < 4; r++)
            row_out(rbase + r, N, lane, acc[r].x, acc[r].y,
                    as0, as1, ad0, ad1, H16, AL, rmax);
    }

    // fold: block-level max of als per head -> 2 atomics (reuse xb as scratch)
    __syncthreads();
    float* red = (float*)xb;
    if (lane == 0)       red[wave * 2 + 0] = rmax;
    else if (lane == 32) red[wave * 2 + 1] = rmax;
    __syncthreads();
    if (t < 2) {
        float m = red[t];
#pragma unroll
        for (int i = 1; i < 8; i++) m = fmaxf(m, red[2 * i + t]);
        atomicMax(&ubp[t], enc_max(m));
    }
}

// ---------------------------------------------------------------------------
// Plain per-dst CSR build (count -> scan -> sliced scatter). Self-loops added.
// ---------------------------------------------------------------------------
__global__ void count_kernel(const int* __restrict__ edst, int* __restrict__ cnt,
                             int E, int N)
{
    int i = blockIdx.x * 256 + threadIdx.x;
    if (i < E)            atomicAdd(&cnt[edst[i]], 1);
    else if (i < E + N)   atomicAdd(&cnt[i - E], 1);   // self loop
}

__global__ void scan_local_kernel(const int* __restrict__ in, int* __restrict__ out,
                                  int* __restrict__ bsum, int n)
{
    __shared__ int sm[1024];
    const int t = threadIdx.x;
    const int i = blockIdx.x * 1024 + t;
    int v = (i < n) ? in[i] : 0;
    sm[t] = v;
    __syncthreads();
    for (int off = 1; off < 1024; off <<= 1) {
        int x = (t >= off) ? sm[t - off] : 0;
        __syncthreads();
        sm[t] += x;
        __syncthreads();
    }
    if (i < n) out[i] = sm[t];
    if (t == 1023) bsum[blockIdx.x] = sm[t];
}

__global__ void scan_excl_single_kernel(int* __restrict__ a, int B)
{
    __shared__ int sm[1024];
    const int t = threadIdx.x;
    int v = (t < B) ? a[t] : 0;
    sm[t] = v;
    __syncthreads();
    for (int off = 1; off < 1024; off <<= 1) {
        int x = (t >= off) ? sm[t - off] : 0;
        __syncthreads();
        sm[t] += x;
        __syncthreads();
    }
    if (t < B) a[t] = sm[t] - v;   // exclusive
}

__global__ void finalize_csr_kernel(const int* __restrict__ incl,
                                    const int* __restrict__ cnt,
                                    const int* __restrict__ bexcl,
                                    int* __restrict__ dstptr, int* __restrict__ cursor,
                                    int N, int Etot)
{
    const int i = blockIdx.x * 1024 + threadIdx.x;
    if (i < N) {
        int v = incl[i] + bexcl[i >> 10] - cnt[i];
        dstptr[i] = v;
        cursor[i] = v;
    }
    if (i == N) dstptr[N] = Etot;
}

// Sliced scatter: blocks with blockIdx%8==s handle dst slice s (-> one XCD by
// round-robin dispatch), so each ssrc cache line is written by one XCD only.
__global__ void scatter_kernel(const int* __restrict__ esrc, const int* __restrict__ edst,
                               int* __restrict__ cursor, int* __restrict__ ssrc,
                               int E, int N, int sliceN, int bps)
{
    const int slice = blockIdx.x & 7;
    const int dlo = slice * sliceN;
    const int dhi = min(N, dlo + sliceN);
    const int Etot = E + N;
    for (int i = (blockIdx.x >> 3) * 256 + (int)threadIdx.x; i < Etot; i += bps * 256) {
        int s, d;
        if (i < E) { s = esrc[i]; d = edst[i]; }
        else       { s = d = i - E; }
        if (d >= dlo && d < dhi) {
            int pos = atomicAdd(&cursor[d], 1);
            ssrc[pos] = s;
        }
    }
}

// ---------------------------------------------------------------------------
// Aggregation, shifted softmax. TWO nodes per wave: lanes 0-31 node A,
// lanes 32-63 node B; lane owns 4 channels (half4 = 8B gathers).
// 3-deep pipeline over 4-edge blocks: srcs t+3 | AL,h16 t+2 | compute t.
// mode 0: out[n,128] = ELU(acc/s + b)   mode 1: out[n,64] = mean_h(acc/s)+b
// ---------------------------------------------------------------------------
__global__ __launch_bounds__(256) void aggregate_kernel(
    const __half* __restrict__ H16, const float* __restrict__ AL,
    const int* __restrict__ dstptr, const int* __restrict__ ssrc,
    const unsigned* __restrict__ ubenc, const float* __restrict__ bias,
    float* __restrict__ out, int N, int mode)
{
    const int wid  = (blockIdx.x * blockDim.x + threadIdx.x) >> 6;
    const int lane = threadIdx.x & 63;
    if (wid * 2 >= N) return;
    const int nl   = lane & 31;               // lane within node
    const int n    = wid * 2 + (lane >> 5);
    const bool act = (n < N);
    const int nn   = act ? n : (N - 1);
    const int beg  = dstptr[nn];
    const int end  = act ? dstptr[nn + 1] : beg;

    const int head = nl >> 4;
    const float ald = AL[(size_t)nn * 4 + 2 + head];
    float ub = dec_max(ubenc[head]) + ald;
    ub = (ub >= 0.f) ? ub : NEG_SLOPE * ub;

    const int nblk = (end - beg + 3) >> 2;
    const int trips = max(nblk, __shfl_xor(nblk, 32, 64));

    float s = 0.f, a0 = 0.f, a1 = 0.f, a2 = 0.f, a3 = 0.f;

    int sA[4];
    float e0[4], e1[4];
    uint2 g0[4], g1[4];

    auto LSRC = [&](int b, int (&sv)[4]) {
#pragma unroll
        for (int k = 0; k < 4; k++) {
            const int idx = beg + 4 * b + k;
            const int v = ssrc[idx];            // padded: safe
            sv[k] = (idx < end) ? v : -1;       // -1 marks masked
        }
    };
    auto LHE = [&](const int (&sv)[4], float (&e)[4], uint2 (&g)[4]) {
#pragma unroll
        for (int k = 0; k < 4; k++) {
            const int src = (sv[k] >= 0) ? sv[k] : 0;
            const float a = AL[(size_t)src * 4 + head];
            e[k] = (sv[k] >= 0) ? a : -__builtin_inff();
            g[k] = ((const uint2*)(H16 + (size_t)src * 128))[nl];
        }
    };

    {   // prologue
        int ta[4], tb[4];
        LSRC(0, ta); LSRC(1, tb); LSRC(2, sA);
        LHE(ta, e0, g0);
        LHE(tb, e1, g1);
    }

    for (int t = 0; t < trips; t++) {
        int sB[4];
        LSRC(t + 3, sB);
        float e2[4]; uint2 g2[4];
        LHE(sA, e2, g2);
#pragma unroll
        for (int k = 0; k < 4; k++) {
            float tt = e0[k] + ald;
            tt = (tt >= 0.f) ? tt : NEG_SLOPE * tt;
            const float p = __expf(tt - ub);    // 0 for masked
            s += p;
            const __half2* ph = (const __half2*)&g0[k];
            const float2 f01 = __half22float2(ph[0]);
            const float2 f23 = __half22float2(ph[1]);
            a0 = fmaf(p, f01.x, a0);
            a1 = fmaf(p, f01.y, a1);
            a2 = fmaf(p, f23.x, a2);
            a3 = fmaf(p, f23.y, a3);
        }
#pragma unroll
        for (int k = 0; k < 4; k++) {
            e0[k] = e1[k]; g0[k] = g1[k];
            e1[k] = e2[k]; g1[k] = g2[k];
            sA[k] = sB[k];
        }
    }

    if (!act) return;
    const float inv = 1.f / s;                  // s > 0 (self loop)
    float o0 = a0 * inv, o1 = a1 * inv, o2 = a2 * inv, o3 = a3 * inv;

    if (mode == 0) {
        const float4 b4 = ((const float4*)bias)[nl];
        o0 += b4.x; o1 += b4.y; o2 += b4.z; o3 += b4.w;
        o0 = (o0 > 0.f) ? o0 : (__expf(o0) - 1.f);
        o1 = (o1 > 0.f) ? o1 : (__expf(o1) - 1.f);
        o2 = (o2 > 0.f) ? o2 : (__expf(o2) - 1.f);
        o3 = (o3 > 0.f) ? o3 : (__expf(o3) - 1.f);
        ((float4*)out)[(size_t)n * 32 + nl] = make_float4(o0, o1, o2, o3);
    } else {
        const float q0 = __shfl_xor(o0, 16, 64);   // swap heads within node
        const float q1 = __shfl_xor(o1, 16, 64);
        const float q2 = __shfl_xor(o2, 16, 64);
        const float q3 = __shfl_xor(o3, 16, 64);
        if (nl < 16) {
            const float4 b4 = ((const float4*)bias)[nl];
            ((float4*)out)[(size_t)n * 16 + nl] =
                make_float4(0.5f * (o0 + q0) + b4.x, 0.5f * (o1 + q1) + b4.y,
                            0.5f * (o2 + q2) + b4.z, 0.5f * (o3 + q3) + b4.w);
        }
    }
}

// ---------------------------------------------------------------------------
extern "C" void kernel_launch(void* const* d_in, const int* in_sizes, int n_in,
                              void* d_out, int out_size, void* d_ws, size_t ws_size,
                              hipStream_t stream)
{
    const float* x   = (const float*)d_in[0];
    const int*   eix = (const int*)d_in[1];   // [2, E] int32
    const float* W1  = (const float*)d_in[2];
    const float* as1 = (const float*)d_in[3];
    const float* ad1 = (const float*)d_in[4];
    const float* b1  = (const float*)d_in[5];
    const float* W2  = (const float*)d_in[6];
    const float* as2 = (const float*)d_in[7];
    const float* ad2 = (const float*)d_in[8];
    const float* b2  = (const float*)d_in[9];
    float* out = (float*)d_out;

    const int N = in_sizes[0] / 128;
    const int E = in_sizes[1] / 2;
    const int Etot = E + N;
    const int* esrc = eix;
    const int* edst = eix + E;

    // ---- workspace layout (~87 MB) ----
    char* p = (char*)d_ws;
    __half*   h16    = (__half*)p;   p += (size_t)N * 128 * 2;
    float*    y1     = (float*)p;    p += (size_t)N * 128 * 4;
    float*    al     = (float*)p;    p += (size_t)N * 4 * 4;
    int*      cnt    = (int*)p;      p += (size_t)N * 4;
    unsigned* ub     = (unsigned*)p; p += 64;                 // [0..1] L1, [2..3] L2
    int*      incl   = (int*)p;      p += (size_t)N * 4;
    int*      dstptr = (int*)p;      p += (size_t)(N + 1) * 4;
    int*      cursor = (int*)p;      p += (size_t)N * 4;
    int*      bs1    = (int*)p;      p += 1024 * 4;
    int*      ssrc   = (int*)p;      p += (size_t)(Etot + 256) * 4;  // pipeline pad

    hipMemsetAsync(cnt, 0, (size_t)N * 4 + 64, stream);   // cnt + ub

    // ---- CSR by destination (shared by both layers) ----
    {
        const int eblocks = (Etot + 255) / 256;
        const int B0 = (N + 1023) / 1024;
        count_kernel<<<eblocks, 256, 0, stream>>>(edst, cnt, E, N);
        scan_local_kernel<<<B0, 1024, 0, stream>>>(cnt, incl, bs1, N);
        scan_excl_single_kernel<<<1, 1024, 0, stream>>>(bs1, B0);
        finalize_csr_kernel<<<(N + 1024) / 1024, 1024, 0, stream>>>(
            incl, cnt, bs1, dstptr, cursor, N, Etot);
        const int sliceN = (N + 7) / 8;
        const int bps = 512;
        scatter_kernel<<<bps * 8, 256, 0, stream>>>(esrc, edst, cursor, ssrc,
                                                    E, N, sliceN, bps);
    }

    const int ggrid = (N + 127) / 128;                 // 128 rows/block
    const int nwaves = (N + 1) / 2;                    // 2 nodes/wave
    const int ablocks = (nwaves + 3) / 4;

    // ---- Layer 1 ----
    gemm_al_kernel<<<ggrid, 512, 0, stream>>>(x, W1, as1, ad1, h16, al, ub, N);
    aggregate_kernel<<<ablocks, 256, 0, stream>>>(h16, al, dstptr, ssrc, ub, b1, y1, N, 0);

    // ---- Layer 2 ----
    gemm_al_kernel<<<ggrid, 512, 0, stream>>>(y1, W2, as2, ad2, h16, al, ub + 2, N);
    aggregate_kernel<<<ablocks, 256, 0, stream>>>(h16, al, dstptr, ssrc, ub + 2, b2, out, N, 1);
}